// Round 6
// baseline (1860.507 us; speedup 1.0000x reference)
//
#include <hip/hip_runtime.h>
#include <math.h>

#define NLOC 100

typedef __attribute__((ext_vector_type(8))) _Float16 half8;
typedef __attribute__((ext_vector_type(4))) float f32x4;

// ---------------- workspace layout (float offsets) ----------------
#define XP_OFF    0            // 160000 f32: padded patches (fallback only)
#define H_OFF     160000       // 51200 f32
#define QKV_OFF   211200       // 204800 f32 [100][2048]
#define OCAT_OFF  416000       // 51200 f32 slots = 100*1024 f16 (fallback only)
#define FFN_OFF   467200       // 102400 f32 slots = 100*2048 f16
#define ACTA_OFF  569600       // 320064 f32 slots = 640128 f16
#define ACTB_OFF  889664       // 320064
#define CWH_OFF   1209728      // 555776 f32 slots = 1111552 f16 conv wts L2..L10
#define CW1_OFF   1765504      // 320 f32: conv1 weights as float4[8*9] (fallback only)
#define WQKVT_OFF 1765824      // 6291456 f32 slots (12*2048*512 f16)
#define WOT_OFF   8057280      // 3145728
#define W1T_OFF   11203008     // 6291456
#define W2T_OFF   17494464     // 6291456
// floats end at 23785920 (byte 95143680)
#define BAR_BYTE_OFF 95143936ull   // barrier region: go(256B) + flags 256*64B
#define BAR_BYTES    20480ull

#define NWG  256
#define NTHR 1024

struct WPack { const float* w[9]; };   // conv layers 2..10

struct KParams {
    const float* x;
    const float* cw1;
    WPack wpk;
    const float* cb0; const float* cb1; const float* cb2; const float* cb3; const float* cb4;
    const float* cb5; const float* cb6; const float* cb7; const float* cb8; const float* cb9;
    const float* Wq; const float* Wk; const float* Wv; const float* Wo;
    const float* W1; const float* b1; const float* W2; const float* b2;
    float* ws;
    float* out;
};

struct TJob {
    const float* src; unsigned short* dst;
    int K, N, mpl, lstride, base, tiles;
};

// ---------------- L2-bypassing (agent-scope) loads for cross-phase data ------
// Agent-scope relaxed atomic loads must be serviced at the cross-XCD coherence
// point (per-XCD L2s are not coherent), so they always see data published by
// the producer's release-store wbl2 — no L2 invalidate needed at barriers.
__device__ __forceinline__ unsigned long long ald64(const void* p) {
    return __hip_atomic_load((const unsigned long long*)p, __ATOMIC_RELAXED, __HIP_MEMORY_SCOPE_AGENT);
}
__device__ __forceinline__ uint4 ald128(const void* p) {
    unsigned long long a = ald64(p);
    unsigned long long b = ald64((const char*)p + 8);
    uint4 r;
    r.x = (unsigned)a; r.y = (unsigned)(a >> 32);
    r.z = (unsigned)b; r.w = (unsigned)(b >> 32);
    return r;
}
__device__ __forceinline__ float aldf(const float* p) {
    unsigned int v = __hip_atomic_load((const unsigned int*)p, __ATOMIC_RELAXED, __HIP_MEMORY_SCOPE_AGENT);
    return __builtin_bit_cast(float, v);
}
__device__ __forceinline__ float2 aldf2(const float* p) {
    unsigned long long v = ald64(p);
    return __builtin_bit_cast(float2, v);
}

// ---------------- fence-light flag/broadcast grid barrier ----------------
// arrival: each block release-stores its padded flag (wbl2 publishes its
// phase outputs; line stays VALID in local L2). block 0's threads poll the
// flags in parallel, then release-store the broadcast 'go'. NO acquire
// fence / L2 invalidate on exit: cross-phase reads use ald* bypass loads,
// weights are write-once so normal cached reads are stale-safe, and L2
// stays warm across barriers.
__device__ __forceinline__ void gbar(unsigned int* go, unsigned int* flags,
                                     unsigned int ph, int wg, int tid)
{
    __syncthreads();
    if (wg == 0) {
        if (tid > 0 && tid < NWG) {
            while (__hip_atomic_load(&flags[tid*16], __ATOMIC_RELAXED, __HIP_MEMORY_SCOPE_AGENT) < ph)
                __builtin_amdgcn_s_sleep(1);
        }
        __syncthreads();
        if (tid == 0)
            __hip_atomic_store(go, ph, __ATOMIC_RELEASE, __HIP_MEMORY_SCOPE_AGENT);
        __syncthreads();
    } else {
        if (tid == 0) {
            __hip_atomic_store(&flags[wg*16], ph, __ATOMIC_RELEASE, __HIP_MEMORY_SCOPE_AGENT);
            while (__hip_atomic_load(go, __ATOMIC_RELAXED, __HIP_MEMORY_SCOPE_AGENT) < ph)
                __builtin_amdgcn_s_sleep(1);
        }
        __syncthreads();
    }
}

// ================= megakernel device helpers =================

// MFMA conv: wave per 16x16 tile, implicit im2col (block-major tile striding)
// A (activations) via bypass loads; B (weights) via normal cached loads.
template<int CIN, int COUT, int KS, int HIN, int WIN, int HOUT, int WOUT, int KPAD, int RELU, int LAST>
__device__ __forceinline__ void convM_dev(const unsigned short* __restrict__ in,
    const unsigned short* __restrict__ wth, const float* __restrict__ bias,
    unsigned short* __restrict__ out, float* __restrict__ hout,
    int gwave, int nwaves, int lane)
{
    constexpr int HW = HOUT*WOUT;
    constexpr int M = 100*HW;
    constexpr int MT = (M + 15)/16;
    constexpr int NT = COUT/16;
    const int mrow = lane & 15, quad = lane >> 4;
    for (int t = gwave; t < MT*NT; t += nwaves) {
        int mt = t % MT, nt = t / MT;
        int mg = mt*16 + mrow; if (mg >= M) mg = M - 1;
        int p = mg / HW, s = mg - p*HW;
        int sy = s / WOUT, sx = s - sy*WOUT;
        const unsigned short* ap = in + ((size_t)((p*HIN + sy)*WIN + sx))*CIN;
        const unsigned short* bp = wth + ((size_t)(nt*16 + mrow))*KPAD + quad*8;
        f32x4 acc = {0.f, 0.f, 0.f, 0.f};
        #pragma unroll 4
        for (int k0 = 0; k0 < KPAD; k0 += 32) {
            int k = k0 + quad*8;
            int kk = k / CIN; if (kk > KS*KS - 1) kk = KS*KS - 1;
            int ky = kk / KS, kx = kk - ky*KS;
            uint4 av = ald128(ap + (ky*WIN + kx)*CIN + (k & (CIN-1)));
            uint4 bv = *(const uint4*)(bp + k0);
            acc = __builtin_amdgcn_mfma_f32_16x16x32_f16(
                __builtin_bit_cast(half8, av), __builtin_bit_cast(half8, bv), acc, 0, 0, 0);
        }
        int n = nt*16 + mrow;
        float bvv = bias[n];
        #pragma unroll
        for (int r = 0; r < 4; ++r) {
            int m = mt*16 + quad*4 + r;
            if (m < M) {
                float v = acc[r] + bvv;
                if (RELU) v = fmaxf(v, 0.f);
                if (LAST) {
                    int pi = m / 10;
                    float pos = 20.f * (float)pi;
                    int dd = n & 255;
                    float inv = powf(10000.f, (float)dd * (1.f/128.f));
                    float ang = pos / inv;
                    v += (n < 256) ? sinf(ang) : cosf(ang);
                    hout[(size_t)m*512 + n] = v;
                } else {
                    _Float16 hv = (_Float16)v;
                    out[(size_t)m*COUT + n] = __builtin_bit_cast(unsigned short, hv);
                }
            }
        }
    }
}

// MFMA GEMM stage: wave per 16x16 tile, full-K (block-major tile striding)
// A (activations) via bypass loads; B (weights) normal; RESID read bypassed.
template<int ABITS, int RELU, int RESID, int OUTH>
__device__ __forceinline__ void gemm_dev(const void* __restrict__ Av, int lda,
    const unsigned short* __restrict__ Bt, int K, int N,
    const float* __restrict__ bias, float* __restrict__ C, unsigned short* __restrict__ Ch,
    int ldc, int gwave, int nwaves, int lane)
{
    const int NT = N >> 4;
    const int tiles = 7*NT;
    const int mrow = lane & 15, quad = lane >> 4;
    for (int t = gwave; t < tiles; t += nwaves) {
        const int mt = t % 7, nt = t / 7;
        int arow = mt*16 + mrow; if (arow > 99) arow = 99;
        const unsigned short* bp = Bt + (size_t)(nt*16 + mrow)*K + quad*8;
        f32x4 acc = {0.f, 0.f, 0.f, 0.f};
        if (ABITS == 16) {
            const unsigned short* ap = (const unsigned short*)Av + (size_t)arow*lda + quad*8;
            #pragma unroll 4
            for (int k = 0; k < K; k += 32) {
                uint4 au = ald128(ap + k);
                uint4 bu = *(const uint4*)(bp + k);
                acc = __builtin_amdgcn_mfma_f32_16x16x32_f16(
                    __builtin_bit_cast(half8, au), __builtin_bit_cast(half8, bu), acc, 0, 0, 0);
            }
        } else {
            const float* ap = (const float*)Av + (size_t)arow*lda + quad*8;
            #pragma unroll 4
            for (int k = 0; k < K; k += 32) {
                float2 g0 = aldf2(ap + k),     g1 = aldf2(ap + k + 2);
                float2 g2 = aldf2(ap + k + 4), g3 = aldf2(ap + k + 6);
                half8 af;
                af[0] = (_Float16)g0.x; af[1] = (_Float16)g0.y;
                af[2] = (_Float16)g1.x; af[3] = (_Float16)g1.y;
                af[4] = (_Float16)g2.x; af[5] = (_Float16)g2.y;
                af[6] = (_Float16)g3.x; af[7] = (_Float16)g3.y;
                uint4 bu = *(const uint4*)(bp + k);
                acc = __builtin_amdgcn_mfma_f32_16x16x32_f16(
                    af, __builtin_bit_cast(half8, bu), acc, 0, 0, 0);
            }
        }
        const int n = nt*16 + mrow;
        const float bv = (bias != nullptr) ? bias[n] : 0.f;
        #pragma unroll
        for (int r = 0; r < 4; ++r) {
            int row = mt*16 + quad*4 + r;
            if (row < 100) {
                float v = acc[r] + bv;
                if (RELU) v = fmaxf(v, 0.f);
                if (RESID) v += aldf(&C[(size_t)row*ldc + n]);
                if (!OUTH) {
                    C[(size_t)row*ldc + n] = v;
                } else {
                    _Float16 hv = (_Float16)v;
                    Ch[(size_t)row*ldc + n] = __builtin_bit_cast(unsigned short, hv);
                }
            }
        }
    }
}

// ================= the cooperative megakernel =================
__global__ __launch_bounds__(NTHR) void megakernel(KParams P)
{
    const int tid = threadIdx.x;
    const int wg  = blockIdx.x;
    const int gthread = wg*NTHR + tid;
    constexpr int nthreads = NWG*NTHR;
    // block-major wave index: tile t -> block t%NWG (spreads every phase
    // across all 256 CUs; round-0/4 mapping parked 200+ CUs per phase).
    const int gwave = (tid >> 6)*NWG + wg;
    constexpr int nwaves = nthreads >> 6;
    const int lane = tid & 63;

    float* ws = P.ws;
    float* hbuf = ws + H_OFF;
    float* qkv  = ws + QKV_OFF;
    unsigned short* ffnb = (unsigned short*)(ws + FFN_OFF);
    unsigned short* aA   = (unsigned short*)(ws + ACTA_OFF);
    unsigned short* aB   = (unsigned short*)(ws + ACTB_OFF);
    unsigned short* cwh  = (unsigned short*)(ws + CWH_OFF);
    unsigned short* wqkvt = (unsigned short*)(ws + WQKVT_OFF);
    unsigned short* wot   = (unsigned short*)(ws + WOT_OFF);
    unsigned short* w1t   = (unsigned short*)(ws + W1T_OFF);
    unsigned short* w2t   = (unsigned short*)(ws + W2T_OFF);
    unsigned int* go    = (unsigned int*)((char*)ws + BAR_BYTE_OFF);
    unsigned int* flags = (unsigned int*)((char*)ws + BAR_BYTE_OFF + 256);

    __shared__ TJob jobs[6];
    __shared__ float w1s[288];      // conv1 weights [oc][kk][c4]
    __shared__ float qs[512];       // attn: staged q row
    __shared__ float oc_s[1024];    // attn: one ocat row
    __shared__ float pb[4][128];    // attn: scores per head
    __shared__ float rr[8];         // attn: max/sum per head

    if (tid == 0) {
        jobs[0] = TJob{P.Wq, wqkvt,  512,  128, 4, 2048*512, 0,        1536};
        jobs[1] = TJob{P.Wk, wqkvt,  512,  128, 4, 2048*512, 512*512,  1536};
        jobs[2] = TJob{P.Wv, wqkvt,  512,  256, 4, 2048*512, 1024*512, 3072};
        jobs[3] = TJob{P.Wo, wot,   1024,  512, 1, 512*1024, 0,        3072};
        jobs[4] = TJob{P.W1, w1t,    512, 2048, 1, 2048*512, 0,        6144};
        jobs[5] = TJob{P.W2, w2t,   2048,  512, 1, 512*2048, 0,        6144};
    }
    if (tid < 288) {
        int c = tid & 3;
        int r = tid >> 2;
        int oc = r / 9, kk = r - oc*9;
        int ky = kk/3, kx = kk - ky*3;
        float v = 0.f;
        if (c < 3) v = P.cw1[((oc*3 + c)*3 + ky)*3 + kx];
        w1s[tid] = v;
    }
    __syncthreads();

    unsigned int bp_ = 0;   // barrier phase counter (uniform across all blocks)

    // ======== PHASE 0: all weight prep + conv1 (independent jobs) ========
    // conv weights L2..L10 -> f16 Bt[oc][Kpad]
    {
        const int Cin[9]   = {8,16,32,32,64,64,128,128,256};
        const int shiftv[9]= {3,4,5,5,6,6,7,7,8};
        const int KSa[9]   = {3,3,3,3,3,3,3,3,2};
        const int Kpad[9]  = {96,160,288,288,576,576,1152,1152,1024};
        const int off[10]  = {0,1536,6656,15872,34304,71168,144896,292352,587264,1111552};
        for (int i = gthread; i < 1111552; i += nthreads) {
            int l = 0;
            while (i >= off[l+1]) ++l;
            int rem = i - off[l];
            int kp = Kpad[l];
            int oc = rem / kp;
            int k  = rem - oc*kp;
            int ci = Cin[l];
            int ic = k & (ci - 1);
            int kk = k >> shiftv[l];
            int ks = KSa[l], k2 = ks*ks;
            float v = 0.f;
            if (kk < k2) {
                int ky = kk / ks, kx = kk - ky*ks;
                v = P.wpk.w[l][((oc*ci + ic)*ks + ky)*ks + kx];
            }
            _Float16 hv = (_Float16)v;
            cwh[i] = __builtin_bit_cast(unsigned short, hv);
        }
    }
    // transformer weight transposes: wave per 64(n) x 32(k) tile
    for (int t = gwave; t < 21504; t += nwaves) {
        int j = 0, rem = t;
        while (rem >= jobs[j].tiles) { rem -= jobs[j].tiles; ++j; }
        const int K = jobs[j].K, N = jobs[j].N;
        const int nb = N >> 6, kb = K >> 5;
        int mat = rem / (nb*kb);
        int r2  = rem - mat*(nb*kb);
        int n0  = (r2 % nb) << 6;
        int k0  = (r2 / nb) << 5;
        const float* s = jobs[j].src + (size_t)mat*K*N;
        int layer = mat / jobs[j].mpl, mi = mat - layer*jobs[j].mpl;
        unsigned short* d = jobs[j].dst + (size_t)layer*jobs[j].lstride + jobs[j].base + (size_t)mi*N*K;
        int nn = n0 + lane;
        #pragma unroll
        for (int half = 0; half < 4; ++half) {
            float v[8];
            #pragma unroll
            for (int kk = 0; kk < 8; ++kk) v[kk] = s[(size_t)(k0 + half*8 + kk)*N + nn];
            unsigned int u[4];
            #pragma unroll
            for (int q = 0; q < 4; ++q) {
                _Float16 a = (_Float16)v[2*q], b = (_Float16)v[2*q+1];
                u[q] = (unsigned int)__builtin_bit_cast(unsigned short, a)
                     | ((unsigned int)__builtin_bit_cast(unsigned short, b) << 16);
            }
            *(uint4*)(d + (size_t)nn*K + k0 + half*8) = make_uint4(u[0],u[1],u[2],u[3]);
        }
    }
    // conv1 directly from x (no staging), weights from LDS
    for (int idx = gthread; idx < 259200; idx += nthreads) {
        int oc = idx & 7;
        int r = idx >> 3;
        int p = r / 324;
        int s = r - p*324;
        int sy = s / 18, sx = s - sy*18;
        int pi = p/10, pj = p - pi*10;
        const float* xb = P.x + (size_t)(pj*20 + sy)*200 + pi*20 + sx;
        float acc = 0.f;
        #pragma unroll
        for (int c = 0; c < 3; ++c) {
            const float* xc = xb + c*40000;
            #pragma unroll
            for (int ky = 0; ky < 3; ++ky)
                #pragma unroll
                for (int kx = 0; kx < 3; ++kx)
                    acc += xc[ky*200 + kx] * w1s[(oc*9 + ky*3 + kx)*4 + c];
        }
        acc += P.cb0[oc];     // no relu after conv1
        _Float16 hv = (_Float16)acc;
        aA[idx] = __builtin_bit_cast(unsigned short, hv);
    }
    gbar(go, flags, ++bp_, wg, tid);
    // one-time full acquire (defensive): weights written in phase 0 by other
    // XCDs; after this they are read-only and stay L2-hot.
    __builtin_amdgcn_fence(__ATOMIC_ACQUIRE, "agent");

    // ======== conv stack ========
    convM_dev<8,  16, 3,18,18,16,16,  96,1,0>(aA, cwh + 0,      P.cb1, aB, nullptr, gwave, nwaves, lane);
    gbar(go, flags, ++bp_, wg, tid);
    convM_dev<16, 32, 3,16,16,14,14, 160,0,0>(aB, cwh + 1536,   P.cb2, aA, nullptr, gwave, nwaves, lane);
    gbar(go, flags, ++bp_, wg, tid);
    convM_dev<32, 32, 3,14,14,12,12, 288,1,0>(aA, cwh + 6656,   P.cb3, aB, nullptr, gwave, nwaves, lane);
    gbar(go, flags, ++bp_, wg, tid);
    convM_dev<32, 64, 3,12,12,10,10, 288,1,0>(aB, cwh + 15872,  P.cb4, aA, nullptr, gwave, nwaves, lane);
    gbar(go, flags, ++bp_, wg, tid);
    convM_dev<64, 64, 3,10,10, 8, 8, 576,1,0>(aA, cwh + 34304,  P.cb5, aB, nullptr, gwave, nwaves, lane);
    gbar(go, flags, ++bp_, wg, tid);
    convM_dev<64,128, 3, 8, 8, 6, 6, 576,1,0>(aB, cwh + 71168,  P.cb6, aA, nullptr, gwave, nwaves, lane);
    gbar(go, flags, ++bp_, wg, tid);
    convM_dev<128,128,3, 6, 6, 4, 4,1152,1,0>(aA, cwh + 144896, P.cb7, aB, nullptr, gwave, nwaves, lane);
    gbar(go, flags, ++bp_, wg, tid);
    convM_dev<128,256,3, 4, 4, 2, 2,1152,1,0>(aB, cwh + 292352, P.cb8, aA, nullptr, gwave, nwaves, lane);
    gbar(go, flags, ++bp_, wg, tid);
    convM_dev<256,512,2, 2, 2, 1, 1,1024,0,1>(aA, cwh + 587264, P.cb9, nullptr, hbuf, gwave, nwaves, lane);
    gbar(go, flags, ++bp_, wg, tid);

    // ======== transformer: 12 layers, 4 barriers each ========
    for (int ln = 0; ln < 12; ++ln) {
        const unsigned short* Bq  = wqkvt + (size_t)ln * (2048*512);
        const unsigned short* Bo  = wot   + (size_t)ln * (512*1024);
        const unsigned short* Bf1 = w1t   + (size_t)ln * (2048*512);
        const unsigned short* Bf2 = w2t   + (size_t)ln * (512*2048);

        // QKV
        gemm_dev<32,0,0,0>(hbuf, 512, Bq, 512, 2048, nullptr, qkv, nullptr, 2048, gwave, nwaves, lane);
        gbar(go, flags, ++bp_, wg, tid);

        // attention + O-projection + residual: 1 row per block, 100 blocks
        if (wg < 100) {
            const int nn = wg;
            const int hh = tid >> 8;        // head 0..3
            const int t  = tid & 255;
            // stage this row's q (512 f32) via bypass loads
            if (tid < 256) {
                float2 qv = aldf2(qkv + (size_t)nn*2048 + tid*2);
                qs[tid*2] = qv.x; qs[tid*2 + 1] = qv.y;
            }
            __syncthreads();
            float sv = 0.f;
            if (t < 100) {
                const float* qp = qs + hh*128;
                const float* kp = qkv + (size_t)t*2048 + 512 + hh*128;
                float s0=0.f, s1=0.f, s2=0.f, s3=0.f;
                #pragma unroll 8
                for (int j = 0; j < 32; ++j) {
                    float2 b0 = aldf2(kp + 4*j), b1 = aldf2(kp + 4*j + 2);
                    s0 += qp[4*j+0]*b0.x; s1 += qp[4*j+1]*b0.y;
                    s2 += qp[4*j+2]*b1.x; s3 += qp[4*j+3]*b1.y;
                }
                sv = (s0+s1+s2+s3) * 0.1f;    // scale = 1/sqrt(N_LOC) quirk
                pb[hh][t] = sv;
            }
            __syncthreads();
            if (t < 64) {                     // one aligned wave per head group
                float m = fmaxf(pb[hh][t], (t+64 < 100) ? pb[hh][t+64] : -1e30f);
                for (int o = 32; o > 0; o >>= 1) m = fmaxf(m, __shfl_down(m, o));
                if (t == 0) rr[hh] = m;
            }
            __syncthreads();
            float mx = rr[hh];
            if (t < 100) pb[hh][t] = expf(sv - mx);
            __syncthreads();
            if (t < 64) {
                float s2 = pb[hh][t] + ((t+64 < 100) ? pb[hh][t+64] : 0.f);
                for (int o = 32; o > 0; o >>= 1) s2 += __shfl_down(s2, o);
                if (t == 0) rr[4+hh] = s2;
            }
            __syncthreads();
            float inv = 1.f / rr[4+hh];
            // PV: all 1024 threads, output element (hh, t), t in 0..255
            {
                const float* vp = qkv + 1024 + hh*256 + t;
                float a0 = 0.f;
                #pragma unroll 4
                for (int m = 0; m < 100; ++m) a0 += pb[hh][m] * aldf(vp + (size_t)m*2048);
                // round through f16 to match the reference path's ocat precision
                oc_s[hh*256 + t] = (float)(_Float16)(a0 * inv);
            }
            __syncthreads();
            // O-projection + residual: 512 outputs over threads 0..511
            if (tid < 512) {
                const int o = tid;
                const unsigned short* wr = Bo + (size_t)o*1024;
                float acc = 0.f;
                #pragma unroll 4
                for (int k2 = 0; k2 < 1024; k2 += 8) {
                    uint4 wu = *(const uint4*)(wr + k2);
                    half8 wf = __builtin_bit_cast(half8, wu);
                    acc += oc_s[k2+0]*(float)wf[0] + oc_s[k2+1]*(float)wf[1]
                         + oc_s[k2+2]*(float)wf[2] + oc_s[k2+3]*(float)wf[3]
                         + oc_s[k2+4]*(float)wf[4] + oc_s[k2+5]*(float)wf[5]
                         + oc_s[k2+6]*(float)wf[6] + oc_s[k2+7]*(float)wf[7];
                }
                float hv0 = aldf(&hbuf[(size_t)nn*512 + o]);
                hbuf[(size_t)nn*512 + o] = hv0 + acc;
            }
        }
        gbar(go, flags, ++bp_, wg, tid);

        // FFN1 (bias+relu, f16 out)
        gemm_dev<32,1,0,1>(hbuf, 512, Bf1, 512, 2048, P.b1 + (size_t)ln*2048, nullptr, ffnb, 2048, gwave, nwaves, lane);
        gbar(go, flags, ++bp_, wg, tid);
        // FFN2 (bias + residual)
        gemm_dev<16,0,1,0>(ffnb, 2048, Bf2, 2048, 512, P.b2 + (size_t)ln*512, hbuf, nullptr, 512, gwave, nwaves, lane);
        gbar(go, flags, ++bp_, wg, tid);
    }

    // ---- final copy ----
    for (int i = gthread; i < 51200; i += nthreads) P.out[i] = aldf(&hbuf[i]);
}

// ================= fallback path: original multi-kernel pipeline =================

__global__ __launch_bounds__(256) void stage_xp(const float* __restrict__ x, float* __restrict__ xp)
{
    int idx = blockIdx.x*256 + threadIdx.x;
    if (idx >= 160000) return;
    int c = idx & 3;
    int idx2 = idx >> 2;
    int p = idx2 / 400;
    int rr = idx2 - p*400;
    int y = rr / 20, xx = rr - y*20;
    int pi = p/10, pj = p - pi*10;
    float v = 0.f;
    if (c < 3) v = x[c*40000 + (pj*20 + y)*200 + pi*20 + xx];
    xp[idx] = v;
}

__global__ __launch_bounds__(256) void cw1repack(const float* __restrict__ w, float* __restrict__ w4)
{
    int idx = threadIdx.x;
    if (idx >= 288) return;
    int c = idx & 3;
    int r = idx >> 2;
    int oc = r / 9, kk = r - oc*9;
    int ky = kk/3, kx = kk - ky*3;
    float v = 0.f;
    if (c < 3) v = w[((oc*3 + c)*3 + ky)*3 + kx];
    w4[idx] = v;
}

__global__ __launch_bounds__(256) void cwrepack(WPack wp, unsigned short* __restrict__ dst)
{
    const int Cin[9]  = {8,16,32,32,64,64,128,128,256};
    const int shift[9]= {3,4,5,5,6,6,7,7,8};
    const int KS[9]   = {3,3,3,3,3,3,3,3,2};
    const int Kpad[9] = {96,160,288,288,576,576,1152,1152,1024};
    const int off[10] = {0,1536,6656,15872,34304,71168,144896,292352,587264,1111552};
    const int total = 1111552;
    for (int i = blockIdx.x*blockDim.x + threadIdx.x; i < total; i += gridDim.x*blockDim.x) {
        int l = 0;
        while (i >= off[l+1]) ++l;
        int rem = i - off[l];
        int kp = Kpad[l];
        int oc = rem / kp;
        int k  = rem - oc*kp;
        int ci = Cin[l];
        int ic = k & (ci - 1);
        int kk = k >> shift[l];
        int ks = KS[l], k2 = ks*ks;
        float v = 0.f;
        if (kk < k2) {
            int ky = kk / ks, kx = kk - ky*ks;
            v = wp.w[l][((oc*ci + ic)*ks + ky)*ks + kx];
        }
        _Float16 hv = (_Float16)v;
        dst[i] = __builtin_bit_cast(unsigned short, hv);
    }
}

__global__ __launch_bounds__(256) void conv1k(const float4* __restrict__ xp4,
    const float4* __restrict__ w4, const float* __restrict__ bias, unsigned short* __restrict__ out)
{
    int idx = blockIdx.x*256 + threadIdx.x;
    if (idx >= 259200) return;
    int oc = idx & 7;
    int r = idx >> 3;
    int p = r / 324;
    int s = r - p*324;
    int sy = s / 18, sx = s - sy*18;
    const float4* ip = xp4 + (size_t)(p*20 + sy)*20 + sx;
    float acc = 0.f;
    #pragma unroll
    for (int ky = 0; ky < 3; ++ky)
        #pragma unroll
        for (int kx = 0; kx < 3; ++kx) {
            float4 iv = ip[ky*20 + kx];
            float4 wv = w4[oc*9 + ky*3 + kx];
            acc += iv.x*wv.x + iv.y*wv.y + iv.z*wv.z;
        }
    acc += bias[oc];
    _Float16 hv = (_Float16)acc;
    out[idx] = __builtin_bit_cast(unsigned short, hv);
}

template<int CIN, int COUT, int KS, int HIN, int WIN, int HOUT, int WOUT, int KPAD, int RELU, int LAST>
__global__ __launch_bounds__(256) void convM(const unsigned short* __restrict__ in,
    const unsigned short* __restrict__ wth, const float* __restrict__ bias,
    unsigned short* __restrict__ out, float* __restrict__ hout)
{
    constexpr int HW = HOUT*WOUT;
    constexpr int M = 100*HW;
    constexpr int MT = (M + 15)/16;
    constexpr int NT = COUT/16;
    int wave = threadIdx.x >> 6, lane = threadIdx.x & 63;
    int t = blockIdx.x*4 + wave;
    if (t >= MT*NT) return;
    int mt = t % MT, nt = t / MT;
    int mrow = lane & 15, quad = lane >> 4;
    int mg = mt*16 + mrow; if (mg >= M) mg = M - 1;
    int p = mg / HW, s = mg - p*HW;
    int sy = s / WOUT, sx = s - sy*WOUT;
    const unsigned short* ap = in + ((size_t)((p*HIN + sy)*WIN + sx))*CIN;
    const unsigned short* bp = wth + ((size_t)(nt*16 + mrow))*KPAD + quad*8;
    f32x4 acc = {0.f, 0.f, 0.f, 0.f};
    #pragma unroll
    for (int k0 = 0; k0 < KPAD; k0 += 32) {
        int k = k0 + quad*8;
        int kk = k / CIN; if (kk > KS*KS - 1) kk = KS*KS - 1;
        int ky = kk / KS, kx = kk - ky*KS;
        uint4 av = *(const uint4*)(ap + (ky*WIN + kx)*CIN + (k & (CIN-1)));
        uint4 bv = *(const uint4*)(bp + k0);
        acc = __builtin_amdgcn_mfma_f32_16x16x32_f16(
            __builtin_bit_cast(half8, av), __builtin_bit_cast(half8, bv), acc, 0, 0, 0);
    }
    int n = nt*16 + mrow;
    float bv = bias[n];
    #pragma unroll
    for (int r = 0; r < 4; ++r) {
        int m = mt*16 + quad*4 + r;
        if (m < M) {
            float v = acc[r] + bv;
            if (RELU) v = fmaxf(v, 0.f);
            if (LAST) {
                int pi = m / 10;
                float pos = 20.f * (float)pi;
                int dd = n & 255;
                float inv = powf(10000.f, (float)dd * (1.f/128.f));
                float ang = pos / inv;
                v += (n < 256) ? sinf(ang) : cosf(ang);
                hout[(size_t)m*512 + n] = v;
            } else {
                _Float16 hv = (_Float16)v;
                out[(size_t)m*COUT + n] = __builtin_bit_cast(unsigned short, hv);
            }
        }
    }
}

__global__ __launch_bounds__(256) void wtrans(
    const float* __restrict__ src, unsigned short* __restrict__ dst,
    int K, int N, int matsPerLayer, int dstLayerStride, int dstBase)
{
    __shared__ float t[32][33];
    int mz = blockIdx.z;
    int layer = mz / matsPerLayer;
    int mi = mz - layer*matsPerLayer;
    const float* s = src + (size_t)mz * K * N;
    unsigned short* d = dst + (size_t)layer*dstLayerStride + dstBase + (size_t)mi * N * K;
    int n0 = blockIdx.x*32, k0 = blockIdx.y*32;
    int tx = threadIdx.x & 31, ty = threadIdx.x >> 5;
    #pragma unroll
    for (int i = 0; i < 32; i += 8) t[ty + i][tx] = s[(size_t)(k0 + ty + i)*N + n0 + tx];
    __syncthreads();
    #pragma unroll
    for (int i = 0; i < 32; i += 8) {
        _Float16 hv = (_Float16)t[tx][ty + i];
        d[(size_t)(n0 + ty + i)*K + k0 + tx] = __builtin_bit_cast(unsigned short, hv);
    }
}

template<int ABITS, int RELU, int ATOMIC, int STOREH>
__global__ __launch_bounds__(256) void gemm16(
    const void* __restrict__ Av, int lda,
    const unsigned short* __restrict__ Bt, int K,
    const float* __restrict__ bias,
    float* __restrict__ C, unsigned short* __restrict__ Ch, int ldc,
    int kchunk)
{
    int lane = threadIdx.x & 63;
    int wave = threadIdx.x >> 6;
    int mrow = lane & 15, quad = lane >> 4;
    int n0 = blockIdx.x*64 + wave*16;
    int m0 = blockIdx.y*16;
    int arow = m0 + mrow; if (arow > 99) arow = 99;
    int k0 = blockIdx.z * kchunk;
    const unsigned short* bp = Bt + (size_t)(n0 + mrow)*K + quad*8 + k0;
    f32x4 acc = {0.f, 0.f, 0.f, 0.f};
    if (ABITS == 16) {
        const unsigned short* ap = (const unsigned short*)Av + (size_t)arow*lda + quad*8 + k0;
        for (int k = 0; k < kchunk; k += 32) {
            uint4 au = *(const uint4*)(ap + k);
            uint4 bu = *(const uint4*)(bp + k);
            acc = __builtin_amdgcn_mfma_f32_16x16x32_f16(
                __builtin_bit_cast(half8, au), __builtin_bit_cast(half8, bu), acc, 0, 0, 0);
        }
    } else {
        const float* ap = (const float*)Av + (size_t)arow*lda + quad*8 + k0;
        for (int k = 0; k < kchunk; k += 32) {
            float4 f0 = *(const float4*)(ap + k);
            float4 f1 = *(const float4*)(ap + k + 4);
            half8 af;
            af[0] = (_Float16)f0.x; af[1] = (_Float16)f0.y;
            af[2] = (_Float16)f0.z; af[3] = (_Float16)f0.w;
            af[4] = (_Float16)f1.x; af[5] = (_Float16)f1.y;
            af[6] = (_Float16)f1.z; af[7] = (_Float16)f1.w;
            uint4 bu = *(const uint4*)(bp + k);
            acc = __builtin_amdgcn_mfma_f32_16x16x32_f16(
                af, __builtin_bit_cast(half8, bu), acc, 0, 0, 0);
        }
    }
    int n = n0 + mrow;
    float bv = (bias != nullptr && blockIdx.z == 0) ? bias[n] : 0.f;
    #pragma unroll
    for (int r = 0; r < 4; ++r) {
        int row = m0 + quad*4 + r;
        if (row < 100) {
            float v = acc[r] + bv;
            if (RELU) v = fmaxf(v, 0.f);
            if (ATOMIC) atomicAdd(&C[(size_t)row*ldc + n], v);
            else if (C != nullptr) C[(size_t)row*ldc + n] = v;
            if (STOREH) {
                _Float16 hv = (_Float16)v;
                Ch[(size_t)row*ldc + n] = __builtin_bit_cast(unsigned short, hv);
            }
        }
    }
}

__global__ __launch_bounds__(256) void attn_kernel(
    const float* __restrict__ qkv, unsigned short* __restrict__ ocat)
{
    __shared__ float qr[128];
    __shared__ float p[100];
    __shared__ float red[2];
    int bx = blockIdx.x;
    int hh = bx / 100, nn = bx - hh*100;
    int t = threadIdx.x;
    if (t < 128) qr[t] = qkv[(size_t)nn*2048 + hh*128 + t];
    __syncthreads();
    float sv = 0.f;
    if (t < 100) {
        const float4* kp = (const float4*)(qkv + (size_t)t*2048 + 512 + hh*128);
        const float4* q4 = (const float4*)qr;
        float s0=0.f, s1=0.f, s2=0.f, s3=0.f;
        #pragma unroll 8
        for (int j = 0; j < 32; ++j) {
            float4 a = q4[j], b = kp[j];
            s0 += a.x*b.x; s1 += a.y*b.y; s2 += a.z*b.z; s3 += a.w*b.w;
        }
        sv = (s0+s1+s2+s3) * 0.1f;
        p[t] = sv;
    }
    __syncthreads();
    if (t < 64) {
        float m = fmaxf(p[t], (t+64 < 100) ? p[t+64] : -1e30f);
        for (int o = 32; o > 0; o >>= 1) m = fmaxf(m, __shfl_down(m, o));
        if (t == 0) red[0] = m;
    }
    __syncthreads();
    float mx = red[0];
    if (t < 100) p[t] = expf(sv - mx);
    __syncthreads();
    if (t < 64) {
        float s = p[t] + ((t+64 < 100) ? p[t+64] : 0.f);
        for (int o = 32; o > 0; o >>= 1) s += __shfl_down(s, o);
        if (t == 0) red[1] = s;
    }
    __syncthreads();
    float inv = 1.0f / red[1];
    const float* vp = qkv + 1024 + hh*256 + t;
    float acc = 0.f;
    #pragma unroll 4
    for (int m = 0; m < 100; ++m) acc += p[m] * vp[(size_t)m*2048];
    _Float16 hv = (_Float16)(acc * inv);
    ocat[(size_t)nn*1024 + hh*256 + t] = __builtin_bit_cast(unsigned short, hv);
}

__global__ __launch_bounds__(256) void copyk(const float* __restrict__ s, float* __restrict__ d, int n)
{
    int i = blockIdx.x*256 + threadIdx.x;
    if (i < n) d[i] = s[i];
}

static void launch_fallback(void* const* d_in, void* d_out, void* d_ws, hipStream_t stream)
{
    const float* x = (const float*)d_in[0];
    const float* cw1 = (const float*)d_in[1];
    const float* cb[10];
    WPack wpk;
    for (int i = 0; i < 10; ++i) cb[i] = (const float*)d_in[2 + 2*i];
    for (int i = 0; i < 9; ++i)  wpk.w[i] = (const float*)d_in[3 + 2*i];
    const float* Wq = (const float*)d_in[21];
    const float* Wk = (const float*)d_in[22];
    const float* Wv = (const float*)d_in[23];
    const float* Wo = (const float*)d_in[24];
    const float* W1 = (const float*)d_in[25];
    const float* b1 = (const float*)d_in[26];
    const float* W2 = (const float*)d_in[27];
    const float* b2 = (const float*)d_in[28];

    float* ws = (float*)d_ws;
    float* xp  = ws + XP_OFF;
    float* h   = ws + H_OFF;
    float* qkv = ws + QKV_OFF;
    unsigned short* ocat = (unsigned short*)(ws + OCAT_OFF);
    unsigned short* ffn  = (unsigned short*)(ws + FFN_OFF);
    unsigned short* aA   = (unsigned short*)(ws + ACTA_OFF);
    unsigned short* aB   = (unsigned short*)(ws + ACTB_OFF);
    unsigned short* cwh  = (unsigned short*)(ws + CWH_OFF);
    float* cw14 = ws + CW1_OFF;
    unsigned short* wqkvt = (unsigned short*)(ws + WQKVT_OFF);
    unsigned short* wot   = (unsigned short*)(ws + WOT_OFF);
    unsigned short* w1t   = (unsigned short*)(ws + W1T_OFF);
    unsigned short* w2t   = (unsigned short*)(ws + W2T_OFF);

    cw1repack<<<2, 256, 0, stream>>>(cw1, cw14);
    cwrepack<<<2172, 256, 0, stream>>>(wpk, cwh);
    wtrans<<<dim3(4, 16, 48),  256, 0, stream>>>(Wq, wqkvt, 512, 128,  4, 2048*512, 0);
    wtrans<<<dim3(4, 16, 48),  256, 0, stream>>>(Wk, wqkvt, 512, 128,  4, 2048*512, 512*512);
    wtrans<<<dim3(8, 16, 48),  256, 0, stream>>>(Wv, wqkvt, 512, 256,  4, 2048*512, 1024*512);
    wtrans<<<dim3(16, 32, 12), 256, 0, stream>>>(Wo, wot,  1024, 512,  1, 512*1024, 0);
    wtrans<<<dim3(64, 16, 12), 256, 0, stream>>>(W1, w1t,   512, 2048, 1, 2048*512, 0);
    wtrans<<<dim3(16, 64, 12), 256, 0, stream>>>(W2, w2t,  2048, 512,  1, 512*2048, 0);

    stage_xp<<<625, 256, 0, stream>>>(x, xp);
    conv1k<<<1013, 256, 0, stream>>>((const float4*)xp, (const float4*)cw14, cb[0], aA);
    convM<8,  16, 3,18,18,16,16,  96,1,0><<<400, 256, 0, stream>>>(aA, cwh + 0,      cb[1], aB, nullptr);
    convM<16, 32, 3,16,16,14,14, 160,0,0><<<613, 256, 0, stream>>>(aB, cwh + 1536,   cb[2], aA, nullptr);
    convM<32, 32, 3,14,14,12,12, 288,1,0><<<450, 256, 0, stream>>>(aA, cwh + 6656,   cb[3], aB, nullptr);
    convM<32, 64, 3,12,12,10,10, 288,1,0><<<625, 256, 0, stream>>>(aB, cwh + 15872,  cb[4], aA, nullptr);
    convM<64, 64, 3,10,10, 8, 8, 576,1,0><<<400, 256, 0, stream>>>(aA, cwh + 34304,  cb[5], aB, nullptr);
    convM<64,128, 3, 8, 8, 6, 6, 576,1,0><<<450, 256, 0, stream>>>(aB, cwh + 71168,  cb[6], aA, nullptr);
    convM<128,128,3, 6, 6, 4, 4,1152,1,0><<<200, 256, 0, stream>>>(aA, cwh + 144896, cb[7], aB, nullptr);
    convM<128,256,3, 4, 4, 2, 2,1152,1,0><<<100, 256, 0, stream>>>(aB, cwh + 292352, cb[8], aA, nullptr);
    convM<256,512,2, 2, 2, 1, 1,1024,0,1><<<56,  256, 0, stream>>>(aA, cwh + 587264, cb[9], nullptr, h);

    for (int n = 0; n < 12; ++n) {
        const unsigned short* Bq  = wqkvt + (size_t)n * 2048 * 512;
        const unsigned short* Bo  = wot   + (size_t)n * 512 * 1024;
        const unsigned short* Bf1 = w1t   + (size_t)n * 2048 * 512;
        const unsigned short* Bf2 = w2t   + (size_t)n * 512 * 2048;
        gemm16<32,0,0,0><<<dim3(32, 7, 1), 256, 0, stream>>>(h, 512, Bq, 512,
            nullptr, qkv, nullptr, 2048, 512);
        attn_kernel<<<400, 256, 0, stream>>>(qkv, ocat);
        gemm16<16,0,1,0><<<dim3(8, 7, 4), 256, 0, stream>>>(ocat, 1024, Bo, 1024,
            nullptr, h, nullptr, 512, 256);
        gemm16<32,1,0,1><<<dim3(32, 7, 1), 256, 0, stream>>>(h, 512, Bf1, 512,
            b1 + (size_t)n*2048, nullptr, ffn, 2048, 512);
        gemm16<16,0,1,0><<<dim3(8, 7, 8), 256, 0, stream>>>(ffn, 2048, Bf2, 2048,
            b2 + (size_t)n*512, h, nullptr, 512, 256);
    }
    copyk<<<200, 256, 0, stream>>>(h, (float*)d_out, NLOC*512);
}

// ---------------- launch ----------------
extern "C" void kernel_launch(void* const* d_in, const int* in_sizes, int n_in,
                              void* d_out, int out_size, void* d_ws, size_t ws_size,
                              hipStream_t stream)
{
    KParams P;
    P.x   = (const float*)d_in[0];
    P.cw1 = (const float*)d_in[1];
    const float* cbs[10];
    for (int i = 0; i < 10; ++i) cbs[i] = (const float*)d_in[2 + 2*i];
    for (int i = 0; i < 9; ++i)  P.wpk.w[i] = (const float*)d_in[3 + 2*i];
    P.cb0 = cbs[0]; P.cb1 = cbs[1]; P.cb2 = cbs[2]; P.cb3 = cbs[3]; P.cb4 = cbs[4];
    P.cb5 = cbs[5]; P.cb6 = cbs[6]; P.cb7 = cbs[7]; P.cb8 = cbs[8]; P.cb9 = cbs[9];
    P.Wq = (const float*)d_in[21];
    P.Wk = (const float*)d_in[22];
    P.Wv = (const float*)d_in[23];
    P.Wo = (const float*)d_in[24];
    P.W1 = (const float*)d_in[25];
    P.b1 = (const float*)d_in[26];
    P.W2 = (const float*)d_in[27];
    P.b2 = (const float*)d_in[28];
    P.ws  = (float*)d_ws;
    P.out = (float*)d_out;

    static int coop = -1;
    if (coop < 0) {
        int v = 0;
        if (hipDeviceGetAttribute(&v, hipDeviceAttributeCooperativeLaunch, 0) != hipSuccess) v = 0;
        coop = v;
    }
    if (coop && ws_size >= BAR_BYTE_OFF + BAR_BYTES) {
        // zero the barrier flags (workspace is re-poisoned between iterations)
        if (hipMemsetAsync((char*)d_ws + BAR_BYTE_OFF, 0, BAR_BYTES, stream) == hipSuccess) {
            void* args[] = { (void*)&P };
            hipError_t e = hipLaunchCooperativeKernel((const void*)megakernel,
                                                      dim3(NWG), dim3(NTHR), (void**)args, 0, stream);
            if (e == hipSuccess) return;
        }
    }
    launch_fallback(d_in, d_out, d_ws, stream);
}

// Round 7
// 1213.271 us; speedup vs baseline: 1.5335x; 1.5335x over previous
//
#include <hip/hip_runtime.h>
#include <math.h>

#define NLOC 100

typedef __attribute__((ext_vector_type(8))) _Float16 half8;
typedef __attribute__((ext_vector_type(4))) float f32x4;

// ---------------- workspace layout (float offsets) ----------------
#define H_OFF     160000       // 51200 f32  (h, fp32)
#define QKV_OFF   211200       // 204800 f32 [100][2048]
#define H16_OFF   416000       // 25600 f32 slots = 100*512 f16 (h rounded to f16)
#define FFN_OFF   467200       // 102400 f32 slots = 100*2048 f16
#define ACTA_OFF  569600       // 320064 f32 slots = 640128 f16
#define ACTB_OFF  889664       // 320064
#define CWH_OFF   1209728      // 555776 f32 slots = 1111552 f16 conv wts L2..L10
#define WQKVT_OFF 1765824      // 6291456 f32 slots (12*2048*512 f16)
#define WOT_OFF   8057280      // 3145728
#define W1T_OFF   11203008     // 6291456
#define W2T_OFF   17494464     // 6291456

struct WPack { const float* w[9]; };   // conv layers 2..10

struct TJob {
    const float* src; unsigned short* dst;
    int K, N, mpl, lstride, base, tiles;
};

struct PrepParams {
    WPack wpk;
    const float* Wq; const float* Wk; const float* Wv; const float* Wo;
    const float* W1; const float* W2;
    float* ws;
};

// ---------------- fused weight prep: conv repack + 6 transposes ----------------
// (phase-0 structure from the megakernel experiments — verified passing r5/r6)
__global__ __launch_bounds__(256) void prep_all(PrepParams PP)
{
    float* ws = PP.ws;
    unsigned short* cwh   = (unsigned short*)(ws + CWH_OFF);
    unsigned short* wqkvt = (unsigned short*)(ws + WQKVT_OFF);
    unsigned short* wot   = (unsigned short*)(ws + WOT_OFF);
    unsigned short* w1t   = (unsigned short*)(ws + W1T_OFF);
    unsigned short* w2t   = (unsigned short*)(ws + W2T_OFF);

    const int tid = threadIdx.x;
    const int gthread = blockIdx.x*256 + tid;
    const int nthreads = gridDim.x*256;
    const int gwave = gthread >> 6;
    const int nwaves = nthreads >> 6;
    const int lane = tid & 63;

    __shared__ TJob jobs[6];
    if (tid == 0) {
        jobs[0] = TJob{PP.Wq, wqkvt,  512,  128, 4, 2048*512, 0,        1536};
        jobs[1] = TJob{PP.Wk, wqkvt,  512,  128, 4, 2048*512, 512*512,  1536};
        jobs[2] = TJob{PP.Wv, wqkvt,  512,  256, 4, 2048*512, 1024*512, 3072};
        jobs[3] = TJob{PP.Wo, wot,   1024,  512, 1, 512*1024, 0,        3072};
        jobs[4] = TJob{PP.W1, w1t,    512, 2048, 1, 2048*512, 0,        6144};
        jobs[5] = TJob{PP.W2, w2t,   2048,  512, 1, 512*2048, 0,        6144};
    }
    __syncthreads();

    // conv weights L2..L10 -> f16 Bt[oc][Kpad], k = kk*Cin + ic
    {
        const int Cin[9]   = {8,16,32,32,64,64,128,128,256};
        const int shiftv[9]= {3,4,5,5,6,6,7,7,8};
        const int KSa[9]   = {3,3,3,3,3,3,3,3,2};
        const int Kpad[9]  = {96,160,288,288,576,576,1152,1152,1024};
        const int off[10]  = {0,1536,6656,15872,34304,71168,144896,292352,587264,1111552};
        for (int i = gthread; i < 1111552; i += nthreads) {
            int l = 0;
            while (i >= off[l+1]) ++l;
            int rem = i - off[l];
            int kp = Kpad[l];
            int oc = rem / kp;
            int k  = rem - oc*kp;
            int ci = Cin[l];
            int ic = k & (ci - 1);
            int kk = k >> shiftv[l];
            int ks = KSa[l], k2 = ks*ks;
            float v = 0.f;
            if (kk < k2) {
                int ky = kk / ks, kx = kk - ky*ks;
                v = PP.wpk.w[l][((oc*ci + ic)*ks + ky)*ks + kx];
            }
            _Float16 hv = (_Float16)v;
            cwh[i] = __builtin_bit_cast(unsigned short, hv);
        }
    }
    // transformer weight transposes: wave per 64(n) x 32(k) tile
    for (int t = gwave; t < 21504; t += nwaves) {
        int j = 0, rem = t;
        while (rem >= jobs[j].tiles) { rem -= jobs[j].tiles; ++j; }
        const int K = jobs[j].K, N = jobs[j].N;
        const int nb = N >> 6, kb = K >> 5;
        int mat = rem / (nb*kb);
        int r2  = rem - mat*(nb*kb);
        int n0  = (r2 % nb) << 6;
        int k0  = (r2 / nb) << 5;
        const float* s = jobs[j].src + (size_t)mat*K*N;
        int layer = mat / jobs[j].mpl, mi = mat - layer*jobs[j].mpl;
        unsigned short* d = jobs[j].dst + (size_t)layer*jobs[j].lstride + jobs[j].base + (size_t)mi*N*K;
        int nn = n0 + lane;
        #pragma unroll
        for (int half = 0; half < 4; ++half) {
            float v[8];
            #pragma unroll
            for (int kk = 0; kk < 8; ++kk) v[kk] = s[(size_t)(k0 + half*8 + kk)*N + nn];
            unsigned int u[4];
            #pragma unroll
            for (int q = 0; q < 4; ++q) {
                _Float16 a = (_Float16)v[2*q], b = (_Float16)v[2*q+1];
                u[q] = (unsigned int)__builtin_bit_cast(unsigned short, a)
                     | ((unsigned int)__builtin_bit_cast(unsigned short, b) << 16);
            }
            *(uint4*)(d + (size_t)nn*K + k0 + half*8) = make_uint4(u[0],u[1],u[2],u[3]);
        }
    }
}

// ---------------- conv1 direct from x (no staging), weights via LDS ----------------
__global__ __launch_bounds__(256) void conv1d(const float* __restrict__ x,
    const float* __restrict__ cw1, const float* __restrict__ bias, unsigned short* __restrict__ out)
{
    __shared__ float w1s[288];
    for (int i = threadIdx.x; i < 288; i += 256) {
        int c = i & 3;
        int r = i >> 2;
        int oc = r / 9, kk = r - oc*9;
        int ky = kk/3, kx = kk - ky*3;
        float v = 0.f;
        if (c < 3) v = cw1[((oc*3 + c)*3 + ky)*3 + kx];
        w1s[i] = v;
    }
    __syncthreads();
    int idx = blockIdx.x*256 + threadIdx.x;
    if (idx >= 259200) return;
    int oc = idx & 7;
    int r = idx >> 3;
    int p = r / 324;
    int s = r - p*324;
    int sy = s / 18, sx = s - sy*18;
    int pi = p/10, pj = p - pi*10;
    const float* xb = x + (size_t)(pj*20 + sy)*200 + pi*20 + sx;
    float acc = 0.f;
    #pragma unroll
    for (int c = 0; c < 3; ++c) {
        const float* xc = xb + c*40000;
        #pragma unroll
        for (int ky = 0; ky < 3; ++ky)
            #pragma unroll
            for (int kx = 0; kx < 3; ++kx)
                acc += xc[ky*200 + kx] * w1s[(oc*9 + ky*3 + kx)*4 + c];
    }
    acc += bias[oc];     // no relu after conv1
    _Float16 hv = (_Float16)acc;
    out[idx] = __builtin_bit_cast(unsigned short, hv);
}

// ---------------- MFMA conv: wave per 16x16 tile, implicit im2col ----------------
template<int CIN, int COUT, int KS, int HIN, int WIN, int HOUT, int WOUT, int KPAD, int RELU, int LAST>
__global__ __launch_bounds__(256) void convM(const unsigned short* __restrict__ in,
    const unsigned short* __restrict__ wth, const float* __restrict__ bias,
    unsigned short* __restrict__ out, float* __restrict__ hout)
{
    constexpr int HW = HOUT*WOUT;
    constexpr int M = 100*HW;
    constexpr int MT = (M + 15)/16;
    constexpr int NT = COUT/16;
    int wave = threadIdx.x >> 6, lane = threadIdx.x & 63;
    int t = blockIdx.x*4 + wave;
    if (t >= MT*NT) return;
    int mt = t % MT, nt = t / MT;
    int mrow = lane & 15, quad = lane >> 4;
    int mg = mt*16 + mrow; if (mg >= M) mg = M - 1;
    int p = mg / HW, s = mg - p*HW;
    int sy = s / WOUT, sx = s - sy*WOUT;
    const unsigned short* ap = in + ((size_t)((p*HIN + sy)*WIN + sx))*CIN;
    const unsigned short* bp = wth + ((size_t)(nt*16 + mrow))*KPAD + quad*8;
    f32x4 acc = {0.f, 0.f, 0.f, 0.f};
    #pragma unroll
    for (int k0 = 0; k0 < KPAD; k0 += 32) {
        int k = k0 + quad*8;
        int kk = k / CIN; if (kk > KS*KS - 1) kk = KS*KS - 1;
        int ky = kk / KS, kx = kk - ky*KS;
        uint4 av = *(const uint4*)(ap + (ky*WIN + kx)*CIN + (k & (CIN-1)));
        uint4 bv = *(const uint4*)(bp + k0);
        acc = __builtin_amdgcn_mfma_f32_16x16x32_f16(
            __builtin_bit_cast(half8, av), __builtin_bit_cast(half8, bv), acc, 0, 0, 0);
    }
    int n = nt*16 + mrow;
    float bv = bias[n];
    #pragma unroll
    for (int r = 0; r < 4; ++r) {
        int m = mt*16 + quad*4 + r;
        if (m < M) {
            float v = acc[r] + bv;
            if (RELU) v = fmaxf(v, 0.f);
            if (LAST) {
                int pi = m / 10;
                float pos = 20.f * (float)pi;
                int dd = n & 255;
                float inv = powf(10000.f, (float)dd * (1.f/128.f));
                float ang = pos / inv;
                v += (n < 256) ? sinf(ang) : cosf(ang);
                hout[(size_t)m*512 + n] = v;
            } else {
                _Float16 hv = (_Float16)v;
                out[(size_t)m*COUT + n] = __builtin_bit_cast(unsigned short, hv);
            }
        }
    }
}

// ---------------- MFMA GEMM (transformer) ----------------
template<int ABITS, int RELU, int ATOMIC, int STOREH>
__global__ __launch_bounds__(256) void gemm16(
    const void* __restrict__ Av, int lda,
    const unsigned short* __restrict__ Bt, int K,
    const float* __restrict__ bias,
    float* __restrict__ C, unsigned short* __restrict__ Ch, int ldc,
    int kchunk)
{
    int lane = threadIdx.x & 63;
    int wave = threadIdx.x >> 6;
    int mrow = lane & 15, quad = lane >> 4;
    int n0 = blockIdx.x*64 + wave*16;
    int m0 = blockIdx.y*16;
    int arow = m0 + mrow; if (arow > 99) arow = 99;
    int k0 = blockIdx.z * kchunk;
    const unsigned short* bp = Bt + (size_t)(n0 + mrow)*K + quad*8 + k0;
    f32x4 acc = {0.f, 0.f, 0.f, 0.f};
    if (ABITS == 16) {
        const unsigned short* ap = (const unsigned short*)Av + (size_t)arow*lda + quad*8 + k0;
        for (int k = 0; k < kchunk; k += 32) {
            uint4 au = *(const uint4*)(ap + k);
            uint4 bu = *(const uint4*)(bp + k);
            acc = __builtin_amdgcn_mfma_f32_16x16x32_f16(
                __builtin_bit_cast(half8, au), __builtin_bit_cast(half8, bu), acc, 0, 0, 0);
        }
    } else {
        const float* ap = (const float*)Av + (size_t)arow*lda + quad*8 + k0;
        for (int k = 0; k < kchunk; k += 32) {
            float4 f0 = *(const float4*)(ap + k);
            float4 f1 = *(const float4*)(ap + k + 4);
            half8 af;
            af[0] = (_Float16)f0.x; af[1] = (_Float16)f0.y;
            af[2] = (_Float16)f0.z; af[3] = (_Float16)f0.w;
            af[4] = (_Float16)f1.x; af[5] = (_Float16)f1.y;
            af[6] = (_Float16)f1.z; af[7] = (_Float16)f1.w;
            uint4 bu = *(const uint4*)(bp + k);
            acc = __builtin_amdgcn_mfma_f32_16x16x32_f16(
                af, __builtin_bit_cast(half8, bu), acc, 0, 0, 0);
        }
    }
    int n = n0 + mrow;
    float bv = (bias != nullptr && blockIdx.z == 0) ? bias[n] : 0.f;
    #pragma unroll
    for (int r = 0; r < 4; ++r) {
        int row = m0 + quad*4 + r;
        if (row < 100) {
            float v = acc[r] + bv;
            if (RELU) v = fmaxf(v, 0.f);
            if (ATOMIC) atomicAdd(&C[(size_t)row*ldc + n], v);
            else if (C != nullptr) C[(size_t)row*ldc + n] = v;
            if (STOREH) {
                _Float16 hv = (_Float16)v;
                Ch[(size_t)row*ldc + n] = __builtin_bit_cast(unsigned short, hv);
            }
        }
    }
}

// ---------------- fused attention + O-projection + residual ----------------
// one block per query row (100 blocks x 1024 threads); verified structure
// from megakernel rounds 5/6 (passed, absmax 0.03125). Emits h (f32) and
// h16 (f16-rounded h) for the following FFN1's f16 A-path.
__global__ __launch_bounds__(1024) void attn_fused(const float* __restrict__ qkv,
    const unsigned short* __restrict__ Bo, float* __restrict__ h, unsigned short* __restrict__ h16)
{
    __shared__ float qs[512];       // staged q row
    __shared__ float oc_s[1024];    // concat attn output (f16-rounded)
    __shared__ float pb[4][128];    // scores per head
    __shared__ float rr[8];         // max/sum per head
    const int nn = blockIdx.x;
    const int tid = threadIdx.x;
    const int hh = tid >> 8;        // head 0..3
    const int t  = tid & 255;
    if (tid < 256) {
        float2 qv = *(const float2*)(qkv + (size_t)nn*2048 + tid*2);
        qs[tid*2] = qv.x; qs[tid*2 + 1] = qv.y;
    }
    __syncthreads();
    float sv = 0.f;
    if (t < 100) {
        const float4* q4 = (const float4*)(qs + hh*128);
        const float4* kp = (const float4*)(qkv + (size_t)t*2048 + 512 + hh*128);
        float s0=0.f, s1=0.f, s2=0.f, s3=0.f;
        #pragma unroll 8
        for (int j = 0; j < 32; ++j) {
            float4 a = q4[j], b = kp[j];
            s0 += a.x*b.x; s1 += a.y*b.y; s2 += a.z*b.z; s3 += a.w*b.w;
        }
        sv = (s0+s1+s2+s3) * 0.1f;    // scale = 1/sqrt(N_LOC) quirk
        pb[hh][t] = sv;
    }
    __syncthreads();
    if (t < 64) {                     // one aligned wave per head
        float m = fmaxf(pb[hh][t], (t+64 < 100) ? pb[hh][t+64] : -1e30f);
        for (int o = 32; o > 0; o >>= 1) m = fmaxf(m, __shfl_down(m, o));
        if (t == 0) rr[hh] = m;
    }
    __syncthreads();
    float mx = rr[hh];
    if (t < 100) pb[hh][t] = expf(sv - mx);
    __syncthreads();
    if (t < 64) {
        float s2 = pb[hh][t] + ((t+64 < 100) ? pb[hh][t+64] : 0.f);
        for (int o = 32; o > 0; o >>= 1) s2 += __shfl_down(s2, o);
        if (t == 0) rr[4+hh] = s2;
    }
    __syncthreads();
    float inv = 1.f / rr[4+hh];
    // PV: all 1024 threads, output element (hh, t)
    {
        const float* vp = qkv + 1024 + hh*256 + t;
        float a0 = 0.f;
        #pragma unroll 4
        for (int m = 0; m < 100; ++m) a0 += pb[hh][m] * vp[(size_t)m*2048];
        // round through f16 to match the reference path's ocat precision
        oc_s[hh*256 + t] = (float)(_Float16)(a0 * inv);
    }
    __syncthreads();
    // O-projection + residual: 512 outputs over threads 0..511
    if (tid < 512) {
        const unsigned short* wr = Bo + (size_t)tid*1024;
        float acc = 0.f;
        #pragma unroll 4
        for (int k2 = 0; k2 < 1024; k2 += 8) {
            uint4 wu = *(const uint4*)(wr + k2);
            half8 wf = __builtin_bit_cast(half8, wu);
            acc += oc_s[k2+0]*(float)wf[0] + oc_s[k2+1]*(float)wf[1]
                 + oc_s[k2+2]*(float)wf[2] + oc_s[k2+3]*(float)wf[3]
                 + oc_s[k2+4]*(float)wf[4] + oc_s[k2+5]*(float)wf[5]
                 + oc_s[k2+6]*(float)wf[6] + oc_s[k2+7]*(float)wf[7];
        }
        float hv = h[(size_t)nn*512 + tid] + acc;
        h[(size_t)nn*512 + tid] = hv;
        _Float16 hf = (_Float16)hv;
        h16[(size_t)nn*512 + tid] = __builtin_bit_cast(unsigned short, hf);
    }
}

// ---------------- final copy ----------------
__global__ __launch_bounds__(256) void copyk(const float* __restrict__ s, float* __restrict__ d, int n)
{
    int i = blockIdx.x*256 + threadIdx.x;
    if (i < n) d[i] = s[i];
}

// ---------------- launch ----------------
extern "C" void kernel_launch(void* const* d_in, const int* in_sizes, int n_in,
                              void* d_out, int out_size, void* d_ws, size_t ws_size,
                              hipStream_t stream)
{
    const float* x = (const float*)d_in[0];
    const float* cw1 = (const float*)d_in[1];
    const float* cb[10];
    WPack wpk;
    for (int i = 0; i < 10; ++i) cb[i] = (const float*)d_in[2 + 2*i];
    for (int i = 0; i < 9; ++i)  wpk.w[i] = (const float*)d_in[3 + 2*i];  // layers 2..10
    const float* Wq = (const float*)d_in[21];
    const float* Wk = (const float*)d_in[22];
    const float* Wv = (const float*)d_in[23];
    const float* Wo = (const float*)d_in[24];
    const float* W1 = (const float*)d_in[25];
    const float* b1 = (const float*)d_in[26];
    const float* W2 = (const float*)d_in[27];
    const float* b2 = (const float*)d_in[28];

    float* ws = (float*)d_ws;
    float* h   = ws + H_OFF;
    float* qkv = ws + QKV_OFF;
    unsigned short* h16  = (unsigned short*)(ws + H16_OFF);
    unsigned short* ffn  = (unsigned short*)(ws + FFN_OFF);
    unsigned short* aA   = (unsigned short*)(ws + ACTA_OFF);
    unsigned short* aB   = (unsigned short*)(ws + ACTB_OFF);
    unsigned short* cwh  = (unsigned short*)(ws + CWH_OFF);
    unsigned short* wqkvt = (unsigned short*)(ws + WQKVT_OFF);
    unsigned short* wot   = (unsigned short*)(ws + WOT_OFF);
    unsigned short* w1t   = (unsigned short*)(ws + W1T_OFF);
    unsigned short* w2t   = (unsigned short*)(ws + W2T_OFF);

    // fused weight prep (replaces 8 kernels)
    PrepParams PP;
    PP.wpk = wpk;
    PP.Wq = Wq; PP.Wk = Wk; PP.Wv = Wv; PP.Wo = Wo; PP.W1 = W1; PP.W2 = W2;
    PP.ws = ws;
    prep_all<<<2048, 256, 0, stream>>>(PP);

    // conv stack (conv1 reads x directly; no staging kernel)
    conv1d<<<1013, 256, 0, stream>>>(x, cw1, cb[0], aA);
    convM<8,  16, 3,18,18,16,16,  96,1,0><<<400, 256, 0, stream>>>(aA, cwh + 0,      cb[1], aB, nullptr);
    convM<16, 32, 3,16,16,14,14, 160,0,0><<<613, 256, 0, stream>>>(aB, cwh + 1536,   cb[2], aA, nullptr);
    convM<32, 32, 3,14,14,12,12, 288,1,0><<<450, 256, 0, stream>>>(aA, cwh + 6656,   cb[3], aB, nullptr);
    convM<32, 64, 3,12,12,10,10, 288,1,0><<<625, 256, 0, stream>>>(aB, cwh + 15872,  cb[4], aA, nullptr);
    convM<64, 64, 3,10,10, 8, 8, 576,1,0><<<400, 256, 0, stream>>>(aA, cwh + 34304,  cb[5], aB, nullptr);
    convM<64,128, 3, 8, 8, 6, 6, 576,1,0><<<450, 256, 0, stream>>>(aB, cwh + 71168,  cb[6], aA, nullptr);
    convM<128,128,3, 6, 6, 4, 4,1152,1,0><<<200, 256, 0, stream>>>(aA, cwh + 144896, cb[7], aB, nullptr);
    convM<128,256,3, 4, 4, 2, 2,1152,1,0><<<100, 256, 0, stream>>>(aB, cwh + 292352, cb[8], aA, nullptr);
    convM<256,512,2, 2, 2, 1, 1,1024,0,1><<<56,  256, 0, stream>>>(aA, cwh + 587264, cb[9], nullptr, h);

    // transformer: 4 kernels per layer (QKV, fused-attn+O+resid, FFN1, FFN2)
    for (int n = 0; n < 12; ++n) {
        const unsigned short* Bq  = wqkvt + (size_t)n * 2048 * 512;
        const unsigned short* Bo  = wot   + (size_t)n * 512 * 1024;
        const unsigned short* Bf1 = w1t   + (size_t)n * 2048 * 512;
        const unsigned short* Bf2 = w2t   + (size_t)n * 512 * 2048;
        gemm16<32,0,0,0><<<dim3(32, 7, 1), 256, 0, stream>>>(h, 512, Bq, 512,
            nullptr, qkv, nullptr, 2048, 512);
        attn_fused<<<100, 1024, 0, stream>>>(qkv, Bo, h, h16);
        gemm16<16,1,0,1><<<dim3(32, 7, 1), 256, 0, stream>>>(h16, 512, Bf1, 512,
            b1 + (size_t)n*2048, nullptr, ffn, 2048, 512);
        gemm16<16,0,1,0><<<dim3(8, 7, 8), 256, 0, stream>>>(ffn, 2048, Bf2, 2048,
            b2 + (size_t)n*512, h, nullptr, 512, 256);
    }
    copyk<<<200, 256, 0, stream>>>(h, (float*)d_out, NLOC*512);
}